// Round 9
// baseline (650.089 us; speedup 1.0000x reference)
//
#include <hip/hip_runtime.h>
#include <hip/hip_bf16.h>
#include <stdint.h>

// Problem constants
#define V 512
#define H 8
#define D 64
#define L 16
#define B 4096

typedef __attribute__((ext_vector_type(8))) short short8;
typedef __attribute__((ext_vector_type(4))) float float4_t;

union __attribute__((aligned(16))) Frag { uint32_t u[4]; short8 s; };

// split fp32 x into bf16 hi + bf16 lo (residual), truncation
__device__ __forceinline__ void split_hl(float x, uint32_t& hi, uint32_t& lo) {
    uint32_t uu = __float_as_uint(x);
    hi = uu >> 16;
    float fl = x - __uint_as_float(uu & 0xffff0000u);
    lo = __float_as_uint(fl) >> 16;
}
// pack (lo16|hi16): hi bf16 in LOW 16 bits, lo bf16 in TOP 16 bits (k-pair order)
__device__ __forceinline__ uint32_t pack_lh(float x) {
    uint32_t uu = __float_as_uint(x);
    uint32_t ha = uu & 0xffff0000u;
    float fl = x - __uint_as_float(ha);
    return (uu >> 16) | (__float_as_uint(fl) & 0xffff0000u);
}
// (bf16(a) low | bf16(b) high), truncation
__device__ __forceinline__ uint32_t pk2(float a, float b) {
    return (__float_as_uint(a) >> 16) | (__float_as_uint(b) & 0xffff0000u);
}

// ---------------------------------------------------------------------------
// Kernel A: qkv = emb0 @ w_qkv   (emb row 0 forced to zero)
// ---------------------------------------------------------------------------
__global__ __launch_bounds__(256) void qkv_kernel(const float* __restrict__ emb,
                                                  const float* __restrict__ w_qkv,
                                                  float* __restrict__ qkv)
{
    const int c = blockIdx.x * 256 + threadIdx.x;   // 0..1535
    const int vbase = blockIdx.y * 64;
    float wcol[64];
#pragma unroll
    for (int k = 0; k < 64; ++k) wcol[k] = w_qkv[k * 1536 + c];
    for (int v = vbase; v < vbase + 64; ++v) {
        if (v == 0) { qkv[c] = 0.0f; continue; }
        float acc = 0.0f;
#pragma unroll
        for (int k = 0; k < 64; ++k) acc = fmaf(emb[v * 64 + k], wcol[k], acc);
        qkv[v * 1536 + c] = acc;
    }
}

// ---------------------------------------------------------------------------
// Kernel B: sim2[q][k][h] = dot(q,k)/8 ; sim2[*][0][*] = -1e9   (h innermost)
// ---------------------------------------------------------------------------
__global__ __launch_bounds__(256) void sim_kernel(const float* __restrict__ qkv,
                                                  float* __restrict__ sim2)
{
    const int t = threadIdx.x;
    const int qb = blockIdx.x, kb = blockIdx.y, h = blockIdx.z;
    const int kj = t & 63;
    const int r0 = __builtin_amdgcn_readfirstlane(t >> 6);   // wave-uniform

    const float* kbase = qkv + (kb * 64 + kj) * 1536 + 512 + h * 64;
    float kv[64];
#pragma unroll
    for (int m = 0; m < 16; ++m)
        *(float4*)&kv[m * 4] = *(const float4*)&kbase[m * 4];

    const float* qbase = qkv + (qb * 64 + r0 * 16) * 1536 + h * 64;
    float acc[16];
#pragma unroll
    for (int ii = 0; ii < 16; ++ii) acc[ii] = 0.0f;
#pragma unroll
    for (int ii = 0; ii < 16; ++ii) {
#pragma unroll
        for (int m = 0; m < 16; ++m) {
            float4 q4 = *(const float4*)&qbase[ii * 1536 + m * 4];
            acc[ii] = fmaf(q4.x, kv[m * 4 + 0], acc[ii]);
            acc[ii] = fmaf(q4.y, kv[m * 4 + 1], acc[ii]);
            acc[ii] = fmaf(q4.z, kv[m * 4 + 2], acc[ii]);
            acc[ii] = fmaf(q4.w, kv[m * 4 + 3], acc[ii]);
        }
    }
    const int kglob = kb * 64 + kj;
#pragma unroll
    for (int ii = 0; ii < 16; ++ii) {
        float val = acc[ii] * 0.125f;
        if (kglob == 0) val = -1.0e9f;
        sim2[(size_t)((qb * 64 + r0 * 16 + ii) * 512 + kglob) * 8 + h] = val;
    }
}

// ---------------------------------------------------------------------------
// Kernel P: pre-pack per-lane MFMA weight fragments into wfrag[64][96]
// ---------------------------------------------------------------------------
__global__ void prep_kernel(const float* __restrict__ w1,
                            const float* __restrict__ w2,
                            const float* __restrict__ w3,
                            uint32_t* __restrict__ wfrag)
{
    const int lane = threadIdx.x;       // 64 threads
    const int lq = lane >> 4, ln = lane & 15;
    uint32_t out[96];
#pragma unroll
    for (int mt = 0; mt < 4; ++mt) {
        const int fout = mt * 16 + ln;
#pragma unroll
        for (int j = 0; j < 4; ++j) {
            uint32_t h0, l0, h1_, l1_;
            split_hl(w1[(2 * j) * 64 + fout], h0, l0);
            split_hl(w1[(2 * j + 1) * 64 + fout], h1_, l1_);
            uint32_t hw = h0 | (h1_ << 16);
            uint32_t lw = l0 | (l1_ << 16);
            out[mt * 4 + j] = (lq == 3) ? 0u : ((lq == 1) ? lw : hw);
        }
    }
#pragma unroll
    for (int mt = 0; mt < 4; ++mt)
#pragma unroll
        for (int s = 0; s < 2; ++s)
#pragma unroll
            for (int j = 0; j < 4; ++j) {
                const int fout = mt * 16 + ln;
                const int fin0 = s * 32 + lq * 8 + 2 * j;
                uint32_t h0, l0, h1_, l1_;
                split_hl(w2[fin0 * 64 + fout], h0, l0);
                split_hl(w2[(fin0 + 1) * 64 + fout], h1_, l1_);
                out[16 + mt * 16 + s * 4 + j]     = h0 | (h1_ << 16);
                out[16 + mt * 16 + 8 + s * 4 + j] = l0 | (l1_ << 16);
            }
#pragma unroll
    for (int s = 0; s < 2; ++s)
#pragma unroll
        for (int j = 0; j < 4; ++j) {
            const int fin0 = s * 32 + lq * 8 + 2 * j;
            float v0 = (ln < 8) ? w3[fin0 * 8 + ln] : 0.0f;
            float v1 = (ln < 8) ? w3[(fin0 + 1) * 8 + ln] : 0.0f;
            uint32_t h0, l0, h1_, l1_;
            split_hl(v0, h0, l0);
            split_hl(v1, h1_, l1_);
            out[80 + s * 4 + j] = h0 | (h1_ << 16);
            out[88 + s * 4 + j] = l0 | (l1_ << 16);
        }
#pragma unroll
    for (int i = 0; i < 96; ++i) wfrag[lane * 96 + i] = out[i];
}

// ---------------------------------------------------------------------------
// Kernel C: gather + softmax + MFMA-PV (v from L2) + LN + MFMA MLP + pooling
// 256 threads (4 waves), 3 blocks/CU (53.3 KB LDS), weights in registers
// ---------------------------------------------------------------------------
__global__ __launch_bounds__(256, 3) void main_kernel(
    const int* __restrict__ inputs,
    const float* __restrict__ qkv, const float* __restrict__ sim2,
    const uint32_t* __restrict__ wfrag,
    const float* __restrict__ gamma, const float* __restrict__ beta,
    const float* __restrict__ b1, const float* __restrict__ b2,
    const float* __restrict__ b3,
    float* __restrict__ wft)
{
    __shared__ int tokS[16];
    // arena: pT u32 [128 rows=h*16+i][17] (phases 2-5); phase6: hb 4 x 1152
    __shared__ __align__(16) uint32_t arena[4608];
    // planes: phase1-2 overlay pS f32 [128][17]; phases 3-6: xh u16 [64][136]
    // @ dword 0, zero-pad @ 4352..4355, xl @ 4356; phase7 overlay partF.
    __shared__ __align__(16) uint32_t planes[8708];

    const int t = threadIdx.x;
    const int b = blockIdx.x;
    const int lane = t & 63;
    const int w = t >> 6;
    const int lq = lane >> 4;
    const int ln = lane & 15;
    ushort* up = (ushort*)planes;

    if (t < 16) tokS[t] = inputs[b * 16 + t];
    if (t < 4) planes[4352 + t] = 0u;    // zero pad for lq==3 B1 reads
    __syncthreads();

    int cnt = 0;
#pragma unroll
    for (int j2 = 0; j2 < 16; ++j2) cnt += (tokS[j2] != 0) ? 1 : 0;
    const float inv_msum = 1.0f / (float)cnt;

    float gam4[4], bet4[4];
#pragma unroll
    for (int dch = 0; dch < 4; ++dch) {
        gam4[dch] = gamma[dch * 16 + ln];
        bet4[dch] = beta[dch * 16 + ln];
    }

    // early v loads for BOTH PV stages (issue now, consume ~2-5K cyc later)
    float v0g[16], v1g[16];
#pragma unroll
    for (int jj = 0; jj < 4; ++jj) {
        const float* basev = qkv + tokS[lq * 4 + jj] * 1536 + 1024 + ln;
#pragma unroll
        for (int dch = 0; dch < 4; ++dch) {
            v0g[dch * 4 + jj] = basev[w * 64 + dch * 16];
            v1g[dch * 4 + jj] = basev[(4 + w) * 64 + dch * 16];
        }
    }

    // phase 1: each thread loads one (i,j) pair's 8 h-scores -> pS
    {
        const int i1 = t >> 4, j1 = t & 15;
        const float* srow = sim2 + (size_t)(tokS[i1] * 512 + tokS[j1]) * 8;
        float4 sa = *(const float4*)srow;
        float4 sb = *(const float4*)(srow + 4);
        float* pS = (float*)planes;          // [128 rows=i*8+h][17]
        pS[(i1 * 8 + 0) * 17 + j1] = sa.x;
        pS[(i1 * 8 + 1) * 17 + j1] = sa.y;
        pS[(i1 * 8 + 2) * 17 + j1] = sa.z;
        pS[(i1 * 8 + 3) * 17 + j1] = sa.w;
        pS[(i1 * 8 + 4) * 17 + j1] = sb.x;
        pS[(i1 * 8 + 5) * 17 + j1] = sb.y;
        pS[(i1 * 8 + 6) * 17 + j1] = sb.z;
        pS[(i1 * 8 + 7) * 17 + j1] = sb.w;
    }
    __syncthreads();

    // phase 2: softmax per (i,h) row -> pT[(h*16+i)][17] packed (ph low|pl high)
    if (t < 128) {
        const float* pS = (const float*)planes;
        float s[16];
#pragma unroll
        for (int j = 0; j < 16; ++j) s[j] = pS[t * 17 + j];
        float m = -3.0e38f;
#pragma unroll
        for (int j = 0; j < 16; ++j) m = fmaxf(m, s[j]);
        float sum = 0.0f;
#pragma unroll
        for (int j = 0; j < 16; ++j) { s[j] = __expf(s[j] - m); sum += s[j]; }
        float inv = 1.0f / sum;
        const int prow = (t & 7) * 16 + (t >> 3);
#pragma unroll
        for (int j = 0; j < 16; ++j) arena[prow * 17 + j] = pack_lh(s[j] * inv);
    }
    __syncthreads();

    // phases 3-5: MFMA-PV + LN; stage s: wave w does head h = 4s+w
    const float4_t zf = {0.0f, 0.0f, 0.0f, 0.0f};
    auto pv_stage = [&](const int s, const float (&vg)[16]) {
        const int h = 4 * s + w;
        Frag A;                 // A[row=i=ln][k=2j+p]: (ph, pl) pairs
#pragma unroll
        for (int jj = 0; jj < 4; ++jj)
            A.u[jj] = arena[(h * 16 + ln) * 17 + lq * 4 + jj];
        float4_t acc[4];
#pragma unroll
        for (int dch = 0; dch < 4; ++dch) {
            Frag B1, B2;        // (vh,vh) and (vl,0)
#pragma unroll
            for (int jj = 0; jj < 4; ++jj) {
                float vv = vg[dch * 4 + jj];
                uint32_t uu = __float_as_uint(vv);
                B1.u[jj] = (uu >> 16) | (uu & 0xffff0000u);
                float vl = vv - __uint_as_float(uu & 0xffff0000u);
                B2.u[jj] = __float_as_uint(vl) >> 16;
            }
            float4_t a = __builtin_amdgcn_mfma_f32_16x16x32_bf16(A.s, B1.s, zf, 0, 0, 0);
            acc[dch]  = __builtin_amdgcn_mfma_f32_16x16x32_bf16(A.s, B2.s, a, 0, 0, 0);
        }
        // LN over d per output row i = lq*4+r; write split x to planes
#pragma unroll
        for (int r = 0; r < 4; ++r) {
            float s1 = acc[0][r] + acc[1][r] + acc[2][r] + acc[3][r];
#pragma unroll
            for (int off = 8; off > 0; off >>= 1) s1 += __shfl_xor(s1, off);
            float mu = s1 * (1.0f / 64.0f);
            float d0 = acc[0][r] - mu, d1 = acc[1][r] - mu;
            float d2 = acc[2][r] - mu, d3 = acc[3][r] - mu;
            float v1 = d0 * d0 + d1 * d1 + d2 * d2 + d3 * d3;
#pragma unroll
            for (int off = 8; off > 0; off >>= 1) v1 += __shfl_xor(v1, off);
            float rinv = 1.0f / sqrtf(v1 * (1.0f / 64.0f) + 1e-6f);
            const int i = lq * 4 + r;
            float dd[4] = {d0, d1, d2, d3};
#pragma unroll
            for (int dch = 0; dch < 4; ++dch) {
                float y = dd[dch] * rinv * gam4[dch] + bet4[dch];
                uint32_t uu = __float_as_uint(y);
                float lo = y - __uint_as_float(uu & 0xffff0000u);
                const int xi = (dch * 16 + ln) * 136 + i * 8 + h;
                up[xi] = (ushort)(uu >> 16);
                up[8712 + xi] = (ushort)(__float_as_uint(lo) >> 16);
            }
        }
    };
    pv_stage(0, v0g);
    pv_stage(1, v1g);
    __syncthreads();

    // ---- phase 6: MLP via split-bf16 MFMA; fragment-native LDS ----
    uint32_t* hb = arena + w * 1152;     // hh: +ln*36 ; hl: +576+ln*36
    const uint4* wfl4 = (const uint4*)(wfrag + lane * 96);

    Frag A1[4], A2h[4][2], A2l[4][2], A3h[2], A3l[2];
#pragma unroll
    for (int mt = 0; mt < 4; ++mt) *(uint4*)A1[mt].u = wfl4[mt];
#pragma unroll
    for (int mt = 0; mt < 4; ++mt)
#pragma unroll
        for (int s2 = 0; s2 < 2; ++s2) {
            *(uint4*)A2h[mt][s2].u = wfl4[4 + mt * 4 + s2];
            *(uint4*)A2l[mt][s2].u = wfl4[4 + mt * 4 + 2 + s2];
        }
#pragma unroll
    for (int s2 = 0; s2 < 2; ++s2) {
        *(uint4*)A3h[s2].u = wfl4[20 + s2];
        *(uint4*)A3l[s2].u = wfl4[22 + s2];
    }
    float b1v[4][4], b2v[4][4], b3v[4];
#pragma unroll
    for (int mt = 0; mt < 4; ++mt) {
        float4 v1 = ((const float4*)b1)[mt * 4 + lq];
        b1v[mt][0] = v1.x; b1v[mt][1] = v1.y; b1v[mt][2] = v1.z; b1v[mt][3] = v1.w;
        float4 v2 = ((const float4*)b2)[mt * 4 + lq];
        b2v[mt][0] = v2.x; b2v[mt][1] = v2.y; b2v[mt][2] = v2.z; b2v[mt][3] = v2.w;
    }
    {
        float4 v3 = ((const float4*)b3)[lq & 1];
        b3v[0] = v3.x; b3v[1] = v3.y; b3v[2] = v3.z; b3v[3] = v3.w;
    }

    float wacc[4][4];
#pragma unroll
    for (int dc = 0; dc < 4; ++dc)
#pragma unroll
        for (int r = 0; r < 4; ++r) wacc[dc][r] = 0.0f;

#pragma unroll 1
    for (int n6 = 0; n6 < 4; ++n6) {
        const int i = w * 4 + n6;
        if (tokS[i] == 0) continue;
#pragma unroll
        for (int dc = 0; dc < 4; ++dc) {
            // B1: one b128 from xh (lq 0,1) / xl (lq 2) / zero pad (lq 3)
            const int xoff = (dc * 16 + ln) * 68 + i * 4;
            const int a1 = (lq < 2) ? xoff : ((lq == 2) ? xoff + 4356 : 4352);
            const uint4 xv = *(const uint4*)&planes[a1];
            Frag B1; B1.u[0] = xv.x; B1.u[1] = xv.y; B1.u[2] = xv.z; B1.u[3] = xv.w;

            float4_t acc[4];
#pragma unroll
            for (int mt = 0; mt < 4; ++mt)
                acc[mt] = __builtin_amdgcn_mfma_f32_16x16x32_bf16(A1[mt].s, B1.s, zf, 0, 0, 0);
            // h1 = relu(acc+b1): pair-pack (even|odd) -> hh/hl b64 writes
#pragma unroll
            for (int mt = 0; mt < 4; ++mt) {
                float v0 = fmaxf(acc[mt][0] + b1v[mt][0], 0.0f);
                float v1f = fmaxf(acc[mt][1] + b1v[mt][1], 0.0f);
                float v2 = fmaxf(acc[mt][2] + b1v[mt][2], 0.0f);
                float v3f = fmaxf(acc[mt][3] + b1v[mt][3], 0.0f);
                uint32_t ph0 = pk2(v0, v1f), ph1 = pk2(v2, v3f);
                float e0 = __uint_as_float(ph0 << 16);
                float e1 = __uint_as_float(ph0 & 0xffff0000u);
                float e2 = __uint_as_float(ph1 << 16);
                float e3 = __uint_as_float(ph1 & 0xffff0000u);
                uint32_t pl0 = pk2(v0 - e0, v1f - e1), pl1 = pk2(v2 - e2, v3f - e3);
                const int wa = ln * 36 + mt * 8 + lq * 2;
                *(uint2*)&hb[wa] = make_uint2(ph0, ph1);
                *(uint2*)&hb[576 + wa] = make_uint2(pl0, pl1);
            }
            // B2: raw b128 reads, zero unpack
            Frag B2h[2], B2l[2];
#pragma unroll
            for (int s2 = 0; s2 < 2; ++s2) {
                const int ra = ln * 36 + s2 * 16 + lq * 4;
                uint4 th = *(const uint4*)&hb[ra];
                uint4 tl = *(const uint4*)&hb[576 + ra];
                B2h[s2].u[0] = th.x; B2h[s2].u[1] = th.y; B2h[s2].u[2] = th.z; B2h[s2].u[3] = th.w;
                B2l[s2].u[0] = tl.x; B2l[s2].u[1] = tl.y; B2l[s2].u[2] = tl.z; B2l[s2].u[3] = tl.w;
            }
#pragma unroll
            for (int mt = 0; mt < 4; ++mt) {
                float4_t a = zf;
                a = __builtin_amdgcn_mfma_f32_16x16x32_bf16(A2h[mt][0].s, B2h[0].s, a, 0, 0, 0);
                a = __builtin_amdgcn_mfma_f32_16x16x32_bf16(A2l[mt][0].s, B2h[0].s, a, 0, 0, 0);
                a = __builtin_amdgcn_mfma_f32_16x16x32_bf16(A2h[mt][0].s, B2l[0].s, a, 0, 0, 0);
                a = __builtin_amdgcn_mfma_f32_16x16x32_bf16(A2h[mt][1].s, B2h[1].s, a, 0, 0, 0);
                a = __builtin_amdgcn_mfma_f32_16x16x32_bf16(A2l[mt][1].s, B2h[1].s, a, 0, 0, 0);
                a = __builtin_amdgcn_mfma_f32_16x16x32_bf16(A2h[mt][1].s, B2l[1].s, a, 0, 0, 0);
                acc[mt] = a;
            }
            // h2 -> same buffers
#pragma unroll
            for (int mt = 0; mt < 4; ++mt) {
                float v0 = fmaxf(acc[mt][0] + b2v[mt][0], 0.0f);
                float v1f = fmaxf(acc[mt][1] + b2v[mt][1], 0.0f);
                float v2 = fmaxf(acc[mt][2] + b2v[mt][2], 0.0f);
                float v3f = fmaxf(acc[mt][3] + b2v[mt][3], 0.0f);
                uint32_t ph0 = pk2(v0, v1f), ph1 = pk2(v2, v3f);
                float e0 = __uint_as_float(ph0 << 16);
                float e1 = __uint_as_float(ph0 & 0xffff0000u);
                float e2 = __uint_as_float(ph1 << 16);
                float e3 = __uint_as_float(ph1 & 0xffff0000u);
                uint32_t pl0 = pk2(v0 - e0, v1f - e1), pl1 = pk2(v2 - e2, v3f - e3);
                const int wa = ln * 36 + mt * 8 + lq * 2;
                *(uint2*)&hb[wa] = make_uint2(ph0, ph1);
                *(uint2*)&hb[576 + wa] = make_uint2(pl0, pl1);
            }
            // B3 + stage 3
            float4_t a3 = zf;
#pragma unroll
            for (int s2 = 0; s2 < 2; ++s2) {
                const int ra = ln * 36 + s2 * 16 + lq * 4;
                uint4 th = *(const uint4*)&hb[ra];
                uint4 tl = *(const uint4*)&hb[576 + ra];
                Frag Bh, Bl;
                Bh.u[0] = th.x; Bh.u[1] = th.y; Bh.u[2] = th.z; Bh.u[3] = th.w;
                Bl.u[0] = tl.x; Bl.u[1] = tl.y; Bl.u[2] = tl.z; Bl.u[3] = tl.w;
                a3 = __builtin_amdgcn_mfma_f32_16x16x32_bf16(A3h[s2].s, Bh.s, a3, 0, 0, 0);
                a3 = __builtin_amdgcn_mfma_f32_16x16x32_bf16(A3l[s2].s, Bh.s, a3, 0, 0, 0);
                a3 = __builtin_amdgcn_mfma_f32_16x16x32_bf16(A3h[s2].s, Bl.s, a3, 0, 0, 0);
            }
#pragma unroll
            for (int r = 0; r < 4; ++r) wacc[dc][r] += a3[r] + b3v[r];
        }
    }

    // phase 7: cross-wave reduce; partF overlays planes
    __syncthreads();
    float* partF = (float*)planes;   // [w][c][d] = [4][8][64]
    if (lq < 2) {
#pragma unroll
        for (int dc = 0; dc < 4; ++dc)
#pragma unroll
            for (int r = 0; r < 4; ++r)
                partF[w * 512 + (lq * 4 + r) * 64 + dc * 16 + ln] = wacc[dc][r];
    }
    __syncthreads();
#pragma unroll
    for (int rep = 0; rep < 2; ++rep) {
        int f = rep * 256 + t;          // f = d*8 + c
        int dd = f >> 3, c = f & 7;
        float s4 = 0.0f;
#pragma unroll
        for (int ww = 0; ww < 4; ++ww) s4 += partF[ww * 512 + c * 64 + dd];
        wft[b * 512 + f] = s4 * inv_msum;
    }
}

// ---------------------------------------------------------------------------
// Kernel D: name_ft = mean over 8 words
// ---------------------------------------------------------------------------
__global__ __launch_bounds__(256) void reduce_kernel(const float* __restrict__ wft,
                                                     float* __restrict__ out)
{
    const int o = blockIdx.x * 256 + threadIdx.x;
    const int g = o >> 9, f = o & 511;
    float s = 0.0f;
#pragma unroll
    for (int ww = 0; ww < 8; ++ww) s += wft[(g * 8 + ww) * 512 + f];
    out[o] = s * 0.125f;
}

// ---------------------------------------------------------------------------
extern "C" void kernel_launch(void* const* d_in, const int* in_sizes, int n_in,
                              void* d_out, int out_size, void* d_ws, size_t ws_size,
                              hipStream_t stream)
{
    const int*   inputs = (const int*)  d_in[0];
    const float* emb    = (const float*)d_in[1];
    const float* w_qkv  = (const float*)d_in[2];
    const float* gam    = (const float*)d_in[3];
    const float* bet    = (const float*)d_in[4];
    const float* w1     = (const float*)d_in[5];
    const float* b1     = (const float*)d_in[6];
    const float* w2     = (const float*)d_in[7];
    const float* b2     = (const float*)d_in[8];
    const float* w3     = (const float*)d_in[9];
    const float* b3     = (const float*)d_in[10];

    float* qkv = (float*)d_ws;                   // 512*1536 f32 = 3MB
    float* sim2 = qkv + 512 * 1536;              // 512*512*8 f32 = 8MB
    float* wft = sim2 + 512 * 512 * 8;           // 4096*512 f32 = 8MB
    uint32_t* wfrag = (uint32_t*)(wft + 4096 * 512);  // 64*96 u32 = 24KB
    float* out = (float*)d_out;

    qkv_kernel  <<<dim3(6, 8),    256, 0, stream>>>(emb, w_qkv, qkv);
    sim_kernel  <<<dim3(8, 8, 8), 256, 0, stream>>>(qkv, sim2);
    prep_kernel <<<1,              64, 0, stream>>>(w1, w2, w3, wfrag);
    main_kernel <<<4096,          256, 0, stream>>>(inputs, qkv, sim2, wfrag,
                                                    gam, bet, b1, b2, b3, wft);
    reduce_kernel<<<1024,         256, 0, stream>>>(wft, out);
}

// Round 10
// 332.567 us; speedup vs baseline: 1.9548x; 1.9548x over previous
//
#include <hip/hip_runtime.h>
#include <hip/hip_bf16.h>
#include <stdint.h>

// Problem constants
#define V 512
#define H 8
#define D 64
#define L 16
#define B 4096

typedef __attribute__((ext_vector_type(8))) short short8;
typedef __attribute__((ext_vector_type(4))) float float4_t;

union __attribute__((aligned(16))) Frag { uint32_t u[4]; short8 s; };

// split fp32 x into bf16 hi + bf16 lo (residual), truncation
__device__ __forceinline__ void split_hl(float x, uint32_t& hi, uint32_t& lo) {
    uint32_t uu = __float_as_uint(x);
    hi = uu >> 16;
    float fl = x - __uint_as_float(uu & 0xffff0000u);
    lo = __float_as_uint(fl) >> 16;
}
// pack (lo16|hi16): hi bf16 in LOW 16 bits, lo bf16 in TOP 16 bits (k-pair order)
__device__ __forceinline__ uint32_t pack_lh(float x) {
    uint32_t uu = __float_as_uint(x);
    uint32_t ha = uu & 0xffff0000u;
    float fl = x - __uint_as_float(ha);
    return (uu >> 16) | (__float_as_uint(fl) & 0xffff0000u);
}
// (bf16(a) low | bf16(b) high), truncation
__device__ __forceinline__ uint32_t pk2(float a, float b) {
    return (__float_as_uint(a) >> 16) | (__float_as_uint(b) & 0xffff0000u);
}

// ---------------------------------------------------------------------------
// Kernel A: qkv = emb0 @ w_qkv   (emb row 0 forced to zero)
// ---------------------------------------------------------------------------
__global__ __launch_bounds__(256) void qkv_kernel(const float* __restrict__ emb,
                                                  const float* __restrict__ w_qkv,
                                                  float* __restrict__ qkv)
{
    const int c = blockIdx.x * 256 + threadIdx.x;   // 0..1535
    const int vbase = blockIdx.y * 64;
    float wcol[64];
#pragma unroll
    for (int k = 0; k < 64; ++k) wcol[k] = w_qkv[k * 1536 + c];
    for (int v = vbase; v < vbase + 64; ++v) {
        if (v == 0) { qkv[c] = 0.0f; continue; }
        float acc = 0.0f;
#pragma unroll
        for (int k = 0; k < 64; ++k) acc = fmaf(emb[v * 64 + k], wcol[k], acc);
        qkv[v * 1536 + c] = acc;
    }
}

// ---------------------------------------------------------------------------
// Kernel B: sim2[q][k][h] = dot(q,k)/8 ; sim2[*][0][*] = -1e9   (h innermost)
// ---------------------------------------------------------------------------
__global__ __launch_bounds__(256) void sim_kernel(const float* __restrict__ qkv,
                                                  float* __restrict__ sim2)
{
    const int t = threadIdx.x;
    const int qb = blockIdx.x, kb = blockIdx.y, h = blockIdx.z;
    const int kj = t & 63;
    const int r0 = __builtin_amdgcn_readfirstlane(t >> 6);   // wave-uniform

    const float* kbase = qkv + (kb * 64 + kj) * 1536 + 512 + h * 64;
    float kv[64];
#pragma unroll
    for (int m = 0; m < 16; ++m)
        *(float4*)&kv[m * 4] = *(const float4*)&kbase[m * 4];

    const float* qbase = qkv + (qb * 64 + r0 * 16) * 1536 + h * 64;
    float acc[16];
#pragma unroll
    for (int ii = 0; ii < 16; ++ii) acc[ii] = 0.0f;
#pragma unroll
    for (int ii = 0; ii < 16; ++ii) {
#pragma unroll
        for (int m = 0; m < 16; ++m) {
            float4 q4 = *(const float4*)&qbase[ii * 1536 + m * 4];
            acc[ii] = fmaf(q4.x, kv[m * 4 + 0], acc[ii]);
            acc[ii] = fmaf(q4.y, kv[m * 4 + 1], acc[ii]);
            acc[ii] = fmaf(q4.z, kv[m * 4 + 2], acc[ii]);
            acc[ii] = fmaf(q4.w, kv[m * 4 + 3], acc[ii]);
        }
    }
    const int kglob = kb * 64 + kj;
#pragma unroll
    for (int ii = 0; ii < 16; ++ii) {
        float val = acc[ii] * 0.125f;
        if (kglob == 0) val = -1.0e9f;
        sim2[(size_t)((qb * 64 + r0 * 16 + ii) * 512 + kglob) * 8 + h] = val;
    }
}

// ---------------------------------------------------------------------------
// Kernel P: pre-pack per-lane MFMA weight fragments into wfrag[64][96]
// ---------------------------------------------------------------------------
__global__ void prep_kernel(const float* __restrict__ w1,
                            const float* __restrict__ w2,
                            const float* __restrict__ w3,
                            uint32_t* __restrict__ wfrag)
{
    const int lane = threadIdx.x;       // 64 threads
    const int lq = lane >> 4, ln = lane & 15;
    uint32_t out[96];
#pragma unroll
    for (int mt = 0; mt < 4; ++mt) {
        const int fout = mt * 16 + ln;
#pragma unroll
        for (int j = 0; j < 4; ++j) {
            uint32_t h0, l0, h1_, l1_;
            split_hl(w1[(2 * j) * 64 + fout], h0, l0);
            split_hl(w1[(2 * j + 1) * 64 + fout], h1_, l1_);
            uint32_t hw = h0 | (h1_ << 16);
            uint32_t lw = l0 | (l1_ << 16);
            out[mt * 4 + j] = (lq == 3) ? 0u : ((lq == 1) ? lw : hw);
        }
    }
#pragma unroll
    for (int mt = 0; mt < 4; ++mt)
#pragma unroll
        for (int s = 0; s < 2; ++s)
#pragma unroll
            for (int j = 0; j < 4; ++j) {
                const int fout = mt * 16 + ln;
                const int fin0 = s * 32 + lq * 8 + 2 * j;
                uint32_t h0, l0, h1_, l1_;
                split_hl(w2[fin0 * 64 + fout], h0, l0);
                split_hl(w2[(fin0 + 1) * 64 + fout], h1_, l1_);
                out[16 + mt * 16 + s * 4 + j]     = h0 | (h1_ << 16);
                out[16 + mt * 16 + 8 + s * 4 + j] = l0 | (l1_ << 16);
            }
#pragma unroll
    for (int s = 0; s < 2; ++s)
#pragma unroll
        for (int j = 0; j < 4; ++j) {
            const int fin0 = s * 32 + lq * 8 + 2 * j;
            float v0 = (ln < 8) ? w3[fin0 * 8 + ln] : 0.0f;
            float v1 = (ln < 8) ? w3[(fin0 + 1) * 8 + ln] : 0.0f;
            uint32_t h0, l0, h1_, l1_;
            split_hl(v0, h0, l0);
            split_hl(v1, h1_, l1_);
            out[80 + s * 4 + j] = h0 | (h1_ << 16);
            out[88 + s * 4 + j] = l0 | (l1_ << 16);
        }
#pragma unroll
    for (int i = 0; i < 96; ++i) wfrag[lane * 96 + i] = out[i];
}

// ---------------------------------------------------------------------------
// Kernel C: gather + softmax + MFMA-PV (v from L2) + LN + MFMA MLP + pooling
// 256 threads (4 waves), 2 blocks/CU (53.3 KB LDS), weights in registers.
// NOTE: (256,2) NOT (256,3) — the ,3 bound caps VGPR at 84 and spills the
// resident weights to scratch (~2 GB HBM traffic, 2.3x regression, R9).
// ---------------------------------------------------------------------------
__global__ __launch_bounds__(256, 2) void main_kernel(
    const int* __restrict__ inputs,
    const float* __restrict__ qkv, const float* __restrict__ sim2,
    const uint32_t* __restrict__ wfrag,
    const float* __restrict__ gamma, const float* __restrict__ beta,
    const float* __restrict__ b1, const float* __restrict__ b2,
    const float* __restrict__ b3,
    float* __restrict__ wft)
{
    __shared__ int tokS[16];
    // arena: pT u32 [128 rows=h*16+i][17] (phases 2-5); phase6: hb 4 x 1152
    __shared__ __align__(16) uint32_t arena[4608];
    // planes: phase1-2 overlay pS f32 [128][17]; phases 3-6: xh u16 [64][136]
    // @ dword 0, zero-pad @ 4352..4355, xl @ 4356; phase7 overlay partF.
    __shared__ __align__(16) uint32_t planes[8708];

    const int t = threadIdx.x;
    const int b = blockIdx.x;
    const int lane = t & 63;
    const int w = t >> 6;
    const int lq = lane >> 4;
    const int ln = lane & 15;
    ushort* up = (ushort*)planes;

    if (t < 16) tokS[t] = inputs[b * 16 + t];
    if (t < 4) planes[4352 + t] = 0u;    // zero pad for lq==3 B1 reads
    __syncthreads();

    int cnt = 0;
#pragma unroll
    for (int j2 = 0; j2 < 16; ++j2) cnt += (tokS[j2] != 0) ? 1 : 0;
    const float inv_msum = 1.0f / (float)cnt;

    float gam4[4], bet4[4];
#pragma unroll
    for (int dch = 0; dch < 4; ++dch) {
        gam4[dch] = gamma[dch * 16 + ln];
        bet4[dch] = beta[dch * 16 + ln];
    }

    // early v loads for BOTH PV stages (issue now, consume ~2-5K cyc later)
    float v0g[16], v1g[16];
#pragma unroll
    for (int jj = 0; jj < 4; ++jj) {
        const float* basev = qkv + tokS[lq * 4 + jj] * 1536 + 1024 + ln;
#pragma unroll
        for (int dch = 0; dch < 4; ++dch) {
            v0g[dch * 4 + jj] = basev[w * 64 + dch * 16];
            v1g[dch * 4 + jj] = basev[(4 + w) * 64 + dch * 16];
        }
    }

    // phase 1: each thread loads one (i,j) pair's 8 h-scores -> pS
    {
        const int i1 = t >> 4, j1 = t & 15;
        const float* srow = sim2 + (size_t)(tokS[i1] * 512 + tokS[j1]) * 8;
        float4 sa = *(const float4*)srow;
        float4 sb = *(const float4*)(srow + 4);
        float* pS = (float*)planes;          // [128 rows=i*8+h][17]
        pS[(i1 * 8 + 0) * 17 + j1] = sa.x;
        pS[(i1 * 8 + 1) * 17 + j1] = sa.y;
        pS[(i1 * 8 + 2) * 17 + j1] = sa.z;
        pS[(i1 * 8 + 3) * 17 + j1] = sa.w;
        pS[(i1 * 8 + 4) * 17 + j1] = sb.x;
        pS[(i1 * 8 + 5) * 17 + j1] = sb.y;
        pS[(i1 * 8 + 6) * 17 + j1] = sb.z;
        pS[(i1 * 8 + 7) * 17 + j1] = sb.w;
    }
    __syncthreads();

    // phase 2: softmax per (i,h) row -> pT[(h*16+i)][17] packed (ph low|pl high)
    if (t < 128) {
        const float* pS = (const float*)planes;
        float s[16];
#pragma unroll
        for (int j = 0; j < 16; ++j) s[j] = pS[t * 17 + j];
        float m = -3.0e38f;
#pragma unroll
        for (int j = 0; j < 16; ++j) m = fmaxf(m, s[j]);
        float sum = 0.0f;
#pragma unroll
        for (int j = 0; j < 16; ++j) { s[j] = __expf(s[j] - m); sum += s[j]; }
        float inv = 1.0f / sum;
        const int prow = (t & 7) * 16 + (t >> 3);
#pragma unroll
        for (int j = 0; j < 16; ++j) arena[prow * 17 + j] = pack_lh(s[j] * inv);
    }
    __syncthreads();

    // phases 3-5: MFMA-PV + LN; stage s: wave w does head h = 4s+w
    const float4_t zf = {0.0f, 0.0f, 0.0f, 0.0f};
    auto pv_stage = [&](const int s, const float (&vg)[16]) {
        const int h = 4 * s + w;
        Frag A;                 // A[row=i=ln][k=2j+p]: (ph, pl) pairs
#pragma unroll
        for (int jj = 0; jj < 4; ++jj)
            A.u[jj] = arena[(h * 16 + ln) * 17 + lq * 4 + jj];
        float4_t acc[4];
#pragma unroll
        for (int dch = 0; dch < 4; ++dch) {
            Frag B1, B2;        // (vh,vh) and (vl,0)
#pragma unroll
            for (int jj = 0; jj < 4; ++jj) {
                float vv = vg[dch * 4 + jj];
                uint32_t uu = __float_as_uint(vv);
                B1.u[jj] = (uu >> 16) | (uu & 0xffff0000u);
                float vl = vv - __uint_as_float(uu & 0xffff0000u);
                B2.u[jj] = __float_as_uint(vl) >> 16;
            }
            float4_t a = __builtin_amdgcn_mfma_f32_16x16x32_bf16(A.s, B1.s, zf, 0, 0, 0);
            acc[dch]  = __builtin_amdgcn_mfma_f32_16x16x32_bf16(A.s, B2.s, a, 0, 0, 0);
        }
        // LN over d per output row i = lq*4+r; write split x to planes
#pragma unroll
        for (int r = 0; r < 4; ++r) {
            float s1 = acc[0][r] + acc[1][r] + acc[2][r] + acc[3][r];
#pragma unroll
            for (int off = 8; off > 0; off >>= 1) s1 += __shfl_xor(s1, off);
            float mu = s1 * (1.0f / 64.0f);
            float d0 = acc[0][r] - mu, d1 = acc[1][r] - mu;
            float d2 = acc[2][r] - mu, d3 = acc[3][r] - mu;
            float v1 = d0 * d0 + d1 * d1 + d2 * d2 + d3 * d3;
#pragma unroll
            for (int off = 8; off > 0; off >>= 1) v1 += __shfl_xor(v1, off);
            float rinv = 1.0f / sqrtf(v1 * (1.0f / 64.0f) + 1e-6f);
            const int i = lq * 4 + r;
            float dd[4] = {d0, d1, d2, d3};
#pragma unroll
            for (int dch = 0; dch < 4; ++dch) {
                float y = dd[dch] * rinv * gam4[dch] + bet4[dch];
                uint32_t uu = __float_as_uint(y);
                float lo = y - __uint_as_float(uu & 0xffff0000u);
                const int xi = (dch * 16 + ln) * 136 + i * 8 + h;
                up[xi] = (ushort)(uu >> 16);
                up[8712 + xi] = (ushort)(__float_as_uint(lo) >> 16);
            }
        }
    };
    pv_stage(0, v0g);
    pv_stage(1, v1g);
    __syncthreads();

    // ---- phase 6: MLP via split-bf16 MFMA; fragment-native LDS ----
    uint32_t* hb = arena + w * 1152;     // hh: +ln*36 ; hl: +576+ln*36
    const uint4* wfl4 = (const uint4*)(wfrag + lane * 96);

    Frag A1[4], A2h[4][2], A2l[4][2], A3h[2], A3l[2];
#pragma unroll
    for (int mt = 0; mt < 4; ++mt) *(uint4*)A1[mt].u = wfl4[mt];
#pragma unroll
    for (int mt = 0; mt < 4; ++mt)
#pragma unroll
        for (int s2 = 0; s2 < 2; ++s2) {
            *(uint4*)A2h[mt][s2].u = wfl4[4 + mt * 4 + s2];
            *(uint4*)A2l[mt][s2].u = wfl4[4 + mt * 4 + 2 + s2];
        }
#pragma unroll
    for (int s2 = 0; s2 < 2; ++s2) {
        *(uint4*)A3h[s2].u = wfl4[20 + s2];
        *(uint4*)A3l[s2].u = wfl4[22 + s2];
    }
    float b1v[4][4], b2v[4][4], b3v[4];
#pragma unroll
    for (int mt = 0; mt < 4; ++mt) {
        float4 v1 = ((const float4*)b1)[mt * 4 + lq];
        b1v[mt][0] = v1.x; b1v[mt][1] = v1.y; b1v[mt][2] = v1.z; b1v[mt][3] = v1.w;
        float4 v2 = ((const float4*)b2)[mt * 4 + lq];
        b2v[mt][0] = v2.x; b2v[mt][1] = v2.y; b2v[mt][2] = v2.z; b2v[mt][3] = v2.w;
    }
    {
        float4 v3 = ((const float4*)b3)[lq & 1];
        b3v[0] = v3.x; b3v[1] = v3.y; b3v[2] = v3.z; b3v[3] = v3.w;
    }

    float wacc[4][4];
#pragma unroll
    for (int dc = 0; dc < 4; ++dc)
#pragma unroll
        for (int r = 0; r < 4; ++r) wacc[dc][r] = 0.0f;

#pragma unroll 1
    for (int n6 = 0; n6 < 4; ++n6) {
        const int i = w * 4 + n6;
        if (tokS[i] == 0) continue;
#pragma unroll
        for (int dc = 0; dc < 4; ++dc) {
            // B1: one b128 from xh (lq 0,1) / xl (lq 2) / zero pad (lq 3)
            const int xoff = (dc * 16 + ln) * 68 + i * 4;
            const int a1 = (lq < 2) ? xoff : ((lq == 2) ? xoff + 4356 : 4352);
            const uint4 xv = *(const uint4*)&planes[a1];
            Frag B1; B1.u[0] = xv.x; B1.u[1] = xv.y; B1.u[2] = xv.z; B1.u[3] = xv.w;

            float4_t acc[4];
#pragma unroll
            for (int mt = 0; mt < 4; ++mt)
                acc[mt] = __builtin_amdgcn_mfma_f32_16x16x32_bf16(A1[mt].s, B1.s, zf, 0, 0, 0);
            // h1 = relu(acc+b1): pair-pack (even|odd) -> hh/hl b64 writes
#pragma unroll
            for (int mt = 0; mt < 4; ++mt) {
                float v0 = fmaxf(acc[mt][0] + b1v[mt][0], 0.0f);
                float v1f = fmaxf(acc[mt][1] + b1v[mt][1], 0.0f);
                float v2 = fmaxf(acc[mt][2] + b1v[mt][2], 0.0f);
                float v3f = fmaxf(acc[mt][3] + b1v[mt][3], 0.0f);
                uint32_t ph0 = pk2(v0, v1f), ph1 = pk2(v2, v3f);
                float e0 = __uint_as_float(ph0 << 16);
                float e1 = __uint_as_float(ph0 & 0xffff0000u);
                float e2 = __uint_as_float(ph1 << 16);
                float e3 = __uint_as_float(ph1 & 0xffff0000u);
                uint32_t pl0 = pk2(v0 - e0, v1f - e1), pl1 = pk2(v2 - e2, v3f - e3);
                const int wa = ln * 36 + mt * 8 + lq * 2;
                *(uint2*)&hb[wa] = make_uint2(ph0, ph1);
                *(uint2*)&hb[576 + wa] = make_uint2(pl0, pl1);
            }
            // B2: raw b128 reads, zero unpack
            Frag B2h[2], B2l[2];
#pragma unroll
            for (int s2 = 0; s2 < 2; ++s2) {
                const int ra = ln * 36 + s2 * 16 + lq * 4;
                uint4 th = *(const uint4*)&hb[ra];
                uint4 tl = *(const uint4*)&hb[576 + ra];
                B2h[s2].u[0] = th.x; B2h[s2].u[1] = th.y; B2h[s2].u[2] = th.z; B2h[s2].u[3] = th.w;
                B2l[s2].u[0] = tl.x; B2l[s2].u[1] = tl.y; B2l[s2].u[2] = tl.z; B2l[s2].u[3] = tl.w;
            }
#pragma unroll
            for (int mt = 0; mt < 4; ++mt) {
                float4_t a = zf;
                a = __builtin_amdgcn_mfma_f32_16x16x32_bf16(A2h[mt][0].s, B2h[0].s, a, 0, 0, 0);
                a = __builtin_amdgcn_mfma_f32_16x16x32_bf16(A2l[mt][0].s, B2h[0].s, a, 0, 0, 0);
                a = __builtin_amdgcn_mfma_f32_16x16x32_bf16(A2h[mt][0].s, B2l[0].s, a, 0, 0, 0);
                a = __builtin_amdgcn_mfma_f32_16x16x32_bf16(A2h[mt][1].s, B2h[1].s, a, 0, 0, 0);
                a = __builtin_amdgcn_mfma_f32_16x16x32_bf16(A2l[mt][1].s, B2h[1].s, a, 0, 0, 0);
                a = __builtin_amdgcn_mfma_f32_16x16x32_bf16(A2h[mt][1].s, B2l[1].s, a, 0, 0, 0);
                acc[mt] = a;
            }
            // h2 -> same buffers
#pragma unroll
            for (int mt = 0; mt < 4; ++mt) {
                float v0 = fmaxf(acc[mt][0] + b2v[mt][0], 0.0f);
                float v1f = fmaxf(acc[mt][1] + b2v[mt][1], 0.0f);
                float v2 = fmaxf(acc[mt][2] + b2v[mt][2], 0.0f);
                float v3f = fmaxf(acc[mt][3] + b2v[mt][3], 0.0f);
                uint32_t ph0 = pk2(v0, v1f), ph1 = pk2(v2, v3f);
                float e0 = __uint_as_float(ph0 << 16);
                float e1 = __uint_as_float(ph0 & 0xffff0000u);
                float e2 = __uint_as_float(ph1 << 16);
                float e3 = __uint_as_float(ph1 & 0xffff0000u);
                uint32_t pl0 = pk2(v0 - e0, v1f - e1), pl1 = pk2(v2 - e2, v3f - e3);
                const int wa = ln * 36 + mt * 8 + lq * 2;
                *(uint2*)&hb[wa] = make_uint2(ph0, ph1);
                *(uint2*)&hb[576 + wa] = make_uint2(pl0, pl1);
            }
            // B3 + stage 3
            float4_t a3 = zf;
#pragma unroll
            for (int s2 = 0; s2 < 2; ++s2) {
                const int ra = ln * 36 + s2 * 16 + lq * 4;
                uint4 th = *(const uint4*)&hb[ra];
                uint4 tl = *(const uint4*)&hb[576 + ra];
                Frag Bh, Bl;
                Bh.u[0] = th.x; Bh.u[1] = th.y; Bh.u[2] = th.z; Bh.u[3] = th.w;
                Bl.u[0] = tl.x; Bl.u[1] = tl.y; Bl.u[2] = tl.z; Bl.u[3] = tl.w;
                a3 = __builtin_amdgcn_mfma_f32_16x16x32_bf16(A3h[s2].s, Bh.s, a3, 0, 0, 0);
                a3 = __builtin_amdgcn_mfma_f32_16x16x32_bf16(A3l[s2].s, Bh.s, a3, 0, 0, 0);
                a3 = __builtin_amdgcn_mfma_f32_16x16x32_bf16(A3h[s2].s, Bl.s, a3, 0, 0, 0);
            }
#pragma unroll
            for (int r = 0; r < 4; ++r) wacc[dc][r] += a3[r] + b3v[r];
        }
    }

    // phase 7: cross-wave reduce; partF overlays planes
    __syncthreads();
    float* partF = (float*)planes;   // [w][c][d] = [4][8][64]
    if (lq < 2) {
#pragma unroll
        for (int dc = 0; dc < 4; ++dc)
#pragma unroll
            for (int r = 0; r < 4; ++r)
                partF[w * 512 + (lq * 4 + r) * 64 + dc * 16 + ln] = wacc[dc][r];
    }
    __syncthreads();
#pragma unroll
    for (int rep = 0; rep < 2; ++rep) {
        int f = rep * 256 + t;          // f = d*8 + c
        int dd = f >> 3, c = f & 7;
        float s4 = 0.0f;
#pragma unroll
        for (int ww = 0; ww < 4; ++ww) s4 += partF[ww * 512 + c * 64 + dd];
        wft[b * 512 + f] = s4 * inv_msum;
    }
}

// ---------------------------------------------------------------------------
// Kernel D: name_ft = mean over 8 words
// ---------------------------------------------------------------------------
__global__ __launch_bounds__(256) void reduce_kernel(const float* __restrict__ wft,
                                                     float* __restrict__ out)
{
    const int o = blockIdx.x * 256 + threadIdx.x;
    const int g = o >> 9, f = o & 511;
    float s = 0.0f;
#pragma unroll
    for (int ww = 0; ww < 8; ++ww) s += wft[(g * 8 + ww) * 512 + f];
    out[o] = s * 0.125f;
}

// ---------------------------------------------------------------------------
extern "C" void kernel_launch(void* const* d_in, const int* in_sizes, int n_in,
                              void* d_out, int out_size, void* d_ws, size_t ws_size,
                              hipStream_t stream)
{
    const int*   inputs = (const int*)  d_in[0];
    const float* emb    = (const float*)d_in[1];
    const float* w_qkv  = (const float*)d_in[2];
    const float* gam    = (const float*)d_in[3];
    const float* bet    = (const float*)d_in[4];
    const float* w1     = (const float*)d_in[5];
    const float* b1     = (const float*)d_in[6];
    const float* w2     = (const float*)d_in[7];
    const float* b2     = (const float*)d_in[8];
    const float* w3     = (const float*)d_in[9];
    const float* b3     = (const float*)d_in[10];

    float* qkv = (float*)d_ws;                   // 512*1536 f32 = 3MB
    float* sim2 = qkv + 512 * 1536;              // 512*512*8 f32 = 8MB
    float* wft = sim2 + 512 * 512 * 8;           // 4096*512 f32 = 8MB
    uint32_t* wfrag = (uint32_t*)(wft + 4096 * 512);  // 64*96 u32 = 24KB
    float* out = (float*)d_out;

    qkv_kernel  <<<dim3(6, 8),    256, 0, stream>>>(emb, w_qkv, qkv);
    sim_kernel  <<<dim3(8, 8, 8), 256, 0, stream>>>(qkv, sim2);
    prep_kernel <<<1,              64, 0, stream>>>(w1, w2, w3, wfrag);
    main_kernel <<<4096,          256, 0, stream>>>(inputs, qkv, sim2, wfrag,
                                                    gam, bet, b1, b2, b3, wft);
    reduce_kernel<<<1024,         256, 0, stream>>>(wft, out);
}